// Round 10
// baseline (236.086 us; speedup 1.0000x reference)
//
#include <hip/hip_runtime.h>
#include <hip/hip_bf16.h>
#include <math.h>

// Problem constants
#define BATCH 2
#define LSEQ 1024
#define DMODEL 1024
#define DINNER 2048
#define DSTATE 16
#define DTRANK 64
#define NROWS (BATCH * LSEQ)   // 2048 token rows
#define XROW 128               // padded x_proj width (96 -> 128)
#define NC 32                  // scan chunks
#define TCH (LSEQ / NC)        // 32 timesteps per chunk
#define NSPL 16                // x_proj split-K slices

typedef __bf16 bf16;
typedef __attribute__((ext_vector_type(8))) __bf16 bf16x8;
typedef __attribute__((ext_vector_type(2))) __bf16 bf16x2;
typedef __attribute__((ext_vector_type(4))) float floatx4;

// ---------------------------------------------------------------------------
// bf16 MFMA GEMM. TM=128, templated TN/BK. global_load_lds width-16 staging
// with XOR-swizzled K-chunks (8-way LDS conflict -> free 2-way).
// Single-buffered 2-phase loop, BK=64: the proven structure.
// The pipeline is LATENCY-BOUND at small grids (R7 counters: 6% occupancy,
// 488 GB/s): every win so far came from raising co-resident blocks/CU
// (R8 split-K out +atomics -4us; R9 conv-fused x_proj 0.5->1 blk/CU -29us).
// R10: TN=64 on in_proj/dt (4 and 2 blk/CU), split-K=4 on out (4 blk/CU).
// Rejected: explicit dbuf (R1), BK=128 (R2), XCD swizzle (R3, L3-resident),
// grid.sync fusion (R5, +143us), redundant in-GEMM reduction (R7, +26us).
// CONVA (x_proj): A-tile = silu(conv(xz)) computed inline during staging --
// zero redundancy since grid.x==1 makes every (y,z) A-slice disjoint.
// MODE 0: C = acc                MODE 1: C = softplus(acc + bias[n])
// MODE 2: C = acc + resid[..]    MODE 4: split-K partial store
// MODE 5: atomicAdd accumulate (C pre-initialized)
// ---------------------------------------------------------------------------
template<int MODE, bool BF16OUT, int TN_, int BK_, bool CONVA>
__global__ __launch_bounds__(256) void gemm_bf16_kernel(
    const bf16* __restrict__ A, int lda,
    const bf16* __restrict__ Bt, int ldb,
    void* __restrict__ Cv, int ldc,
    int Ksplit,
    const float* __restrict__ bias,
    const float* __restrict__ resid, int ldr,
    const bf16* __restrict__ xzc,     // CONVA: xz base (x half)
    const float* __restrict__ cw,     // CONVA: conv_w [DINNER][4]
    const float* __restrict__ cb,     // CONVA: conv_b
    bf16* __restrict__ xcout)         // CONVA: xc side-output
{
    constexpr int TMc  = 128;
    constexpr int CA   = BK_ / 8;                  // chunks per row
    constexpr int ISSA = TMc * BK_ * 2 / 4096;     // 4-KB issues for A
    constexpr int ISSB = TN_ * BK_ * 2 / 4096;
    constexpr int NB   = TN_ / 32;                 // B frags per wave
    constexpr int NH   = BK_ / 32;                 // K halves per iter

    __shared__ __attribute__((aligned(16))) bf16 As[TMc * BK_];
    __shared__ __attribute__((aligned(16))) bf16 Bs[TN_ * BK_];

    const int tid  = threadIdx.x;
    const int lane = tid & 63;
    const int wave = tid >> 6;
    const int l15  = lane & 15;
    const int quad = lane >> 4;
    const int wm   = (wave >> 1) * 64;
    const int wn   = (wave & 1) * (TN_ / 2);

    const int row0 = blockIdx.y * TMc;
    const int col0 = blockIdx.x * TN_;
    const long kbase = (long)blockIdx.z * Ksplit;

    const bf16* gA[ISSA]; bf16* lA[ISSA];
    const bf16* gB[ISSB]; bf16* lB[ISSB];
    if constexpr (!CONVA) {
        #pragma unroll
        for (int i = 0; i < ISSA; ++i) {
            int c = i * 256 + wave * 64 + lane;
            int r = c / CA;
            int kc = (c % CA) ^ (r % CA);
            gA[i] = A + (size_t)(row0 + r) * lda + kbase + kc * 8;
            lA[i] = As + (size_t)(i * 256 + wave * 64) * 8;
        }
    }
    #pragma unroll
    for (int i = 0; i < ISSB; ++i) {
        int c = i * 256 + wave * 64 + lane;
        int r = c / CA;
        int kc = (c % CA) ^ (r % CA);
        gB[i] = Bt + (size_t)(col0 + r) * ldb + kbase + kc * 8;
        lB[i] = Bs + (size_t)(i * 256 + wave * 64) * 8;
    }

    floatx4 acc[4][NB];
    #pragma unroll
    for (int i = 0; i < 4; ++i)
        #pragma unroll
        for (int j = 0; j < NB; ++j)
            acc[i][j] = (floatx4){0.f, 0.f, 0.f, 0.f};

    const int kiters = Ksplit / BK_;
    for (int kk = 0; kk < kiters; ++kk) {
        __syncthreads();
        if constexpr (!CONVA) {
            #pragma unroll
            for (int i = 0; i < ISSA; ++i) {
                __builtin_amdgcn_global_load_lds(
                    (const __attribute__((address_space(1))) void*)gA[i],
                    (__attribute__((address_space(3))) void*)lA[i], 16, 0, 0);
                gA[i] += BK_;
            }
        }
        #pragma unroll
        for (int i = 0; i < ISSB; ++i) {
            __builtin_amdgcn_global_load_lds(
                (const __attribute__((address_space(1))) void*)gB[i],
                (__attribute__((address_space(3))) void*)lB[i], 16, 0, 0);
            gB[i] += BK_;
        }
        if constexpr (CONVA) {
            // A-tile = silu(conv(xz)) per 8-channel chunk; swizzled As write
            // (matches reader (h*4+quad)^(r&7)); side-write xc.
            const int chan0 = (int)kbase + kk * BK_;
            #pragma unroll
            for (int p = 0; p < (TMc * CA) / 256; ++p) {
                int f  = tid + 256 * p;
                int r  = f >> 3;
                int c8 = f & 7;
                int row = row0 + r;
                int l   = row & (LSEQ - 1);
                int ch  = chan0 + c8 * 8;
                const bf16* xp = xzc + (size_t)row * (2 * DINNER) + ch;
                float4 cb0 = *(const float4*)&cb[ch];
                float4 cb1 = *(const float4*)&cb[ch + 4];
                float a[8] = {cb0.x, cb0.y, cb0.z, cb0.w,
                              cb1.x, cb1.y, cb1.z, cb1.w};
                float w0[8], w1[8], w2[8], w3[8];
                #pragma unroll
                for (int i = 0; i < 8; ++i) {
                    float4 w = *(const float4*)&cw[(size_t)(ch + i) * 4];
                    w0[i] = w.x; w1[i] = w.y; w2[i] = w.z; w3[i] = w.w;
                }
                {
                    bf16x8 t = *(const bf16x8*)xp;
                    #pragma unroll
                    for (int i = 0; i < 8; ++i) a[i] += (float)t[i] * w3[i];
                }
                if (l >= 1) {
                    bf16x8 t = *(const bf16x8*)(xp - 2 * DINNER);
                    #pragma unroll
                    for (int i = 0; i < 8; ++i) a[i] += (float)t[i] * w2[i];
                }
                if (l >= 2) {
                    bf16x8 t = *(const bf16x8*)(xp - 4 * DINNER);
                    #pragma unroll
                    for (int i = 0; i < 8; ++i) a[i] += (float)t[i] * w1[i];
                }
                if (l >= 3) {
                    bf16x8 t = *(const bf16x8*)(xp - 6 * DINNER);
                    #pragma unroll
                    for (int i = 0; i < 8; ++i) a[i] += (float)t[i] * w0[i];
                }
                bf16x8 o;
                #pragma unroll
                for (int i = 0; i < 8; ++i) {
                    float s = a[i] / (1.0f + __expf(-a[i]));
                    o[i] = (bf16)s;
                }
                *(bf16x8*)&As[(size_t)r * BK_ + ((c8 ^ (r & 7)) * 8)] = o;
                *(bf16x8*)&xcout[(size_t)row * DINNER + ch] = o;
            }
        }
        __syncthreads();

        #pragma unroll
        for (int h = 0; h < NH; ++h) {
            bf16x8 af[4], bfr[NB];
            #pragma unroll
            for (int i = 0; i < 4; ++i) {
                int r = wm + i * 16 + l15;
                af[i] = *(const bf16x8*)&As[(size_t)r * BK_ +
                          (((h * 4 + quad) ^ (r % CA)) * 8)];
            }
            #pragma unroll
            for (int j = 0; j < NB; ++j) {
                int r = wn + j * 16 + l15;
                bfr[j] = *(const bf16x8*)&Bs[(size_t)r * BK_ +
                           (((h * 4 + quad) ^ (r % CA)) * 8)];
            }
            #pragma unroll
            for (int i = 0; i < 4; ++i)
                #pragma unroll
                for (int j = 0; j < NB; ++j)
                    acc[i][j] = __builtin_amdgcn_mfma_f32_16x16x32_bf16(
                                    af[i], bfr[j], acc[i][j], 0, 0, 0);
        }
    }

    #pragma unroll
    for (int i = 0; i < 4; ++i) {
        #pragma unroll
        for (int j = 0; j < NB; ++j) {
            const int gn = col0 + wn + j * 16 + l15;
            #pragma unroll
            for (int r = 0; r < 4; ++r) {
                const int gm = row0 + wm + i * 16 + quad * 4 + r;
                float v = acc[i][j][r];
                if (MODE == 1) {
                    v += bias[gn];
                    // softplus via raw v_exp/v_log (no OCML): ln(1+e^v)
                    if (v < 20.0f) {
                        float e = __builtin_amdgcn_exp2f(v * 1.4426950408889634f);
                        v = 0.6931471805599453f * __builtin_amdgcn_logf(1.0f + e);
                    }
                }
                if (MODE == 2) v += resid[(size_t)gm * ldr + gn];
                if (MODE == 4) {
                    ((float*)Cv)[(size_t)blockIdx.z * ldr + (size_t)gm * ldc + gn] = v;
                } else if (MODE == 5) {
                    unsafeAtomicAdd((float*)Cv + (size_t)gm * ldc + gn, v);
                } else if (BF16OUT) {
                    ((bf16*)Cv)[(size_t)gm * ldc + gn] = (bf16)v;
                } else {
                    ((float*)Cv)[(size_t)gm * ldc + gn] = v;
                }
            }
        }
    }
}

// ---------------------------------------------------------------------------
// Fused prep: 4 weight transposes (fp32 -> bf16, transposed, zero-pad),
// RMSNorm, and out-init (out <- x0 for the split-K out GEMM).
// ---------------------------------------------------------------------------
__global__ __launch_bounds__(256) void prep_kernel(
    const float* __restrict__ W_in,  bf16* __restrict__ WinT,
    const float* __restrict__ W_x,   bf16* __restrict__ WxT,
    const float* __restrict__ W_dt,  bf16* __restrict__ WdtT,
    const float* __restrict__ W_out, bf16* __restrict__ WoutT,
    const float* __restrict__ x0, const float* __restrict__ norm_w,
    bf16* __restrict__ h, float* __restrict__ out_init)
{
    __shared__ float smem[32 * 33];
    const int bid = blockIdx.x;
    const int tid = threadIdx.x;

    if (bid < 6528) {
        const float* W; bf16* Wt; int K, N, Npad, bx, by;
        if (bid < 4096)      { W = W_in;  Wt = WinT;  K = 1024; N = 4096; Npad = 4096; bx = bid & 127, by = bid >> 7; }
        else if (bid < 4352) { int l = bid - 4096; W = W_x;  Wt = WxT;  K = 2048; N = 96;   Npad = 128;  bx = l & 3,  by = l >> 2; }
        else if (bid < 4480) { int l = bid - 4352; W = W_dt; Wt = WdtT; K = 64;   N = 2048; Npad = 2048; bx = l & 63, by = l >> 6; }
        else                 { int l = bid - 4480; W = W_out;Wt = WoutT;K = 2048; N = 1024; Npad = 1024; bx = l & 31, by = l >> 5; }
        float (*tile)[33] = (float(*)[33])smem;
        const int n0 = bx * 32, k0 = by * 32;
        const int tx = tid & 31, ty = tid >> 5;
        #pragma unroll
        for (int i = 0; i < 32; i += 8) {
            int k = k0 + ty + i, n = n0 + tx;
            tile[ty + i][tx] = (k < K && n < N) ? W[(size_t)k * N + n] : 0.0f;
        }
        __syncthreads();
        #pragma unroll
        for (int i = 0; i < 32; i += 8) {
            int n = n0 + ty + i, k = k0 + tx;
            if (n < Npad && k < K)
                Wt[(size_t)n * K + k] = (bf16)tile[tx][ty + i];
        }
    } else if (bid < 8576) {
        const int row = bid - 6528;
        const float* xr = x0 + (size_t)row * DMODEL;
        float4 v = *(const float4*)(xr + tid * 4);
        float ss = v.x * v.x + v.y * v.y + v.z * v.z + v.w * v.w;
        #pragma unroll
        for (int m = 32; m >= 1; m >>= 1) ss += __shfl_xor(ss, m);
        if ((tid & 63) == 0) smem[tid >> 6] = ss;
        __syncthreads();
        float total = smem[0] + smem[1] + smem[2] + smem[3];
        float scale = rsqrtf(total * (1.0f / DMODEL) + 1e-5f);
        float4 wv = *(const float4*)(norm_w + tid * 4);
        union { bf16 b[4]; uint2 u; } pk;
        pk.b[0] = (bf16)(v.x * scale * wv.x);
        pk.b[1] = (bf16)(v.y * scale * wv.y);
        pk.b[2] = (bf16)(v.z * scale * wv.z);
        pk.b[3] = (bf16)(v.w * scale * wv.w);
        *(uint2*)(h + (size_t)row * DMODEL + tid * 4) = pk.u;
    } else {
        // out <- x0 (8 MB float4 copy)
        size_t idx = ((size_t)(bid - 8576) * 256 + tid) * 4;
        *(float4*)(out_init + idx) = *(const float4*)(x0 + idx);
    }
}

// ---------------------------------------------------------------------------
// Reduce x_proj split-K partials: sum NSPL slices of [NROWS][128].
// cols 0..63 -> dt_bf (bf16), cols 64..95 -> BC fp32 [NROWS][32].
// ---------------------------------------------------------------------------
__global__ __launch_bounds__(256) void xproj_reduce_kernel(
    const float* __restrict__ Pw, bf16* __restrict__ dt,
    float* __restrict__ BC)
{
    int idx = blockIdx.x * 256 + threadIdx.x;   // NROWS*128
    int row = idx >> 7, c = idx & 127;
    float s = 0.0f;
    #pragma unroll
    for (int k = 0; k < NSPL; ++k)
        s += Pw[(size_t)k * NROWS * XROW + idx];
    if (c < 64) dt[(size_t)row * 64 + c] = (bf16)s;
    else if (c < 96) BC[(size_t)row * 32 + (c - 64)] = s;
}

// ---------------------------------------------------------------------------
// Chunked selective scan. Lane = (b, chunk, d); 16 states in registers.
// Phase 1: S = local final state; chunk decay product in log2 domain.
// Combine: chunk-serial fixup. Phase 2: re-run from true init, fused ymod.
// exp path: Ad prefolded by log2(e); raw v_exp_f32 via __builtin_amdgcn_exp2f
// (NOT exp2f -- the OCML wrapper's denormal fixup cost ~18us, R1-R3 lesson).
// ---------------------------------------------------------------------------
template<bool FINAL>
__global__ __launch_bounds__(256) void scan_chunk_kernel(
    const bf16* __restrict__ delta,
    const bf16* __restrict__ xc,
    const float* __restrict__ BC,
    const float* __restrict__ A,
    float* __restrict__ Pbuf,
    float* __restrict__ Sbuf,
    const bf16* __restrict__ xz,
    const float* __restrict__ Dp,
    bf16* __restrict__ ybf)
{
    __shared__ float sBC[TCH][32];
    const int tid   = threadIdx.x;
    const int chunk = blockIdx.x;
    const int d     = blockIdx.y * 256 + tid;
    const int b     = blockIdx.z;
    const int row0  = b * LSEQ + chunk * TCH;

    {
        int t = tid >> 3, c4 = (tid & 7) * 4;
        *(float4*)&sBC[t][c4] = *(const float4*)&BC[(size_t)(row0 + t) * 32 + c4];
    }

    const float L2E = 1.4426950408889634f;
    float Ad[16];
    #pragma unroll
    for (int j = 0; j < 4; ++j) {
        float4 av = *(const float4*)&A[(size_t)d * DSTATE + j * 4];
        Ad[j*4+0] = av.x * L2E; Ad[j*4+1] = av.y * L2E;
        Ad[j*4+2] = av.z * L2E; Ad[j*4+3] = av.w * L2E;
    }

    const size_t psbase = ((size_t)(b * NC + chunk) * DSTATE) * DINNER + d;
    float S[16];
    float sumdv = 0.0f;
    if (FINAL) {
        #pragma unroll
        for (int n = 0; n < 16; ++n) S[n] = Sbuf[psbase + (size_t)n * DINNER];
    } else {
        #pragma unroll
        for (int n = 0; n < 16; ++n) S[n] = 0.0f;
    }
    float Dpd = FINAL ? Dp[d] : 0.0f;

    __syncthreads();

    #pragma unroll 2
    for (int t = 0; t < TCH; ++t) {
        const size_t row = (size_t)(row0 + t);
        float dv = (float)delta[row * DINNER + d];
        float xv = (float)xc[row * DINNER + d];
        float u  = dv * xv;
        float yp[4] = {0.f, 0.f, 0.f, 0.f};
        #pragma unroll
        for (int n = 0; n < 16; ++n) {
            float dA = __builtin_amdgcn_exp2f(dv * Ad[n]);  // bare v_exp_f32
            S[n] = dA * S[n] + u * sBC[t][n];
            if (FINAL) yp[n & 3] += S[n] * sBC[t][16 + n];
        }
        if (FINAL) {
            float y = (yp[0] + yp[1]) + (yp[2] + yp[3]);
            float res = (float)xz[row * (2 * DINNER) + DINNER + d];
            float sres = res / (1.0f + __expf(-res));
            ybf[row * DINNER + d] = (bf16)((y + xv * Dpd) * sres);
        } else {
            sumdv += dv;
        }
    }

    if (!FINAL) {
        #pragma unroll
        for (int n = 0; n < 16; ++n) {
            Pbuf[psbase + (size_t)n * DINNER] = __builtin_amdgcn_exp2f(sumdv * Ad[n]);
            Sbuf[psbase + (size_t)n * DINNER] = S[n];
        }
    }
}

// Per-(b,n,d) serial combine over chunks: Sbuf[k] <- true initial state.
__global__ __launch_bounds__(256) void scan_combine_kernel(
    const float* __restrict__ Pbuf, float* __restrict__ Sbuf)
{
    int gid = blockIdx.x * 256 + threadIdx.x;   // B * 16 * DINNER = 65536
    int b = gid >> 15;
    int nd = gid & 32767;
    float carry = 0.0f;
    for (int k = 0; k < NC; ++k) {
        size_t off = ((size_t)(b * NC + k) << 15) + nd;
        float pk = Pbuf[off];
        float sk = Sbuf[off];
        Sbuf[off] = carry;
        carry = pk * carry + sk;
    }
}

// ---------------------------------------------------------------------------
extern "C" void kernel_launch(void* const* d_in, const int* in_sizes, int n_in,
                              void* d_out, int out_size, void* d_ws, size_t ws_size,
                              hipStream_t stream)
{
    const float* x0     = (const float*)d_in[0];
    const float* norm_w = (const float*)d_in[1];
    const float* W_in   = (const float*)d_in[2];   // [1024,4096]
    const float* conv_w = (const float*)d_in[3];
    const float* conv_b = (const float*)d_in[4];
    const float* W_x    = (const float*)d_in[5];   // [2048,96]
    const float* W_dt   = (const float*)d_in[6];   // [64,2048]
    const float* b_dt   = (const float*)d_in[7];
    const float* A      = (const float*)d_in[8];
    const float* Dp     = (const float*)d_in[9];
    const float* W_out  = (const float*)d_in[10];  // [2048,1024]
    float* out = (float*)d_out;

    // Workspace layout (~84 MB)
    char* p = (char*)d_ws;
    bf16*  xz_bf = (bf16*)p;            p += (size_t)NROWS * 2 * DINNER * 2;        // 16MB
    float* Pw    = (float*)p;           p += (size_t)NSPL * NROWS * XROW * 4;       // 16MB
    float* BC    = (float*)p;           p += (size_t)NROWS * 32 * 4;                // 0.25MB
    bf16*  delta = (bf16*)p;            p += (size_t)NROWS * DINNER * 2;            // 8MB
    float* Pbuf  = (float*)p;           p += (size_t)BATCH * NC * DINNER * 16 * 4;  // 8MB
    float* Sbuf  = (float*)p;           p += (size_t)BATCH * NC * DINNER * 16 * 4;  // 8MB
    bf16*  h_bf  = (bf16*)p;            p += (size_t)NROWS * DMODEL * 2;            // 4MB
    bf16*  xc_bf = (bf16*)p;            p += (size_t)NROWS * DINNER * 2;            // 8MB
    bf16*  y_bf  = (bf16*)p;            p += (size_t)NROWS * DINNER * 2;            // 8MB
    bf16*  WinT  = (bf16*)p;            p += (size_t)(2*DINNER) * DMODEL * 2;       // 8MB
    bf16*  WxT   = (bf16*)p;            p += (size_t)XROW * DINNER * 2;             // 0.5MB
    bf16*  WdtT  = (bf16*)p;            p += (size_t)DINNER * DTRANK * 2;           // 0.25MB
    bf16*  WoutT = (bf16*)p;            p += (size_t)DMODEL * DINNER * 2;           // 4MB
    bf16*  dt_bf = (bf16*)p;            p += (size_t)NROWS * DTRANK * 2;            // 0.25MB

    // 1. Fused prep: weight transposes + RMSNorm + out<-x0 init
    prep_kernel<<<10624, 256, 0, stream>>>(W_in, WinT, W_x, WxT, W_dt, WdtT,
                                           W_out, WoutT, x0, norm_w, h_bf, out);

    // 2. xz = h @ W_in  [2048,1024]x[1024,4096] -> bf16
    //    TN=64: 1024 blocks = 4 blk/CU (was 2) -- deeper latency hiding.
    gemm_bf16_kernel<0, true, 64, 64, false><<<dim3(64, 16, 1), 256, 0, stream>>>(
        h_bf, DMODEL, WinT, DMODEL, xz_bf, 2*DINNER, DMODEL, nullptr, nullptr, 0,
        nullptr, nullptr, nullptr, nullptr);

    // 3. x_proj split-K=16 with fused conv+silu A-staging -> Pw slices + xc
    gemm_bf16_kernel<4, false, 128, 64, true><<<dim3(1, 16, NSPL), 256, 0, stream>>>(
        nullptr, 0, WxT, DINNER, Pw, XROW, DINNER / NSPL, nullptr, nullptr, NROWS * XROW,
        xz_bf, conv_w, conv_b, xc_bf);

    // 3b. reduce partials -> dt_bf + BC
    xproj_reduce_kernel<<<(NROWS * XROW) / 256, 256, 0, stream>>>(Pw, dt_bf, BC);

    // 4. delta = softplus(dt @ W_dt + b_dt) -> bf16
    //    TN=64: 512 blocks = 2 blk/CU (was 1) -- this kernel is pure
    //    prologue latency (1 K-iter), so block count directly hides it.
    gemm_bf16_kernel<1, true, 64, 64, false><<<dim3(32, 16, 1), 256, 0, stream>>>(
        dt_bf, DTRANK, WdtT, DTRANK, delta, DINNER, DTRANK, b_dt, nullptr, 0,
        nullptr, nullptr, nullptr, nullptr);

    // 5. chunked selective scan (+ fused ymod) -> y_bf
    dim3 sgrid(NC, DINNER / 256, BATCH);
    scan_chunk_kernel<false><<<sgrid, 256, 0, stream>>>(
        delta, xc_bf, BC, A, Pbuf, Sbuf, nullptr, nullptr, nullptr);
    scan_combine_kernel<<<(BATCH * DINNER * DSTATE) / 256, 256, 0, stream>>>(Pbuf, Sbuf);
    scan_chunk_kernel<true><<<sgrid, 256, 0, stream>>>(
        delta, xc_bf, BC, A, Pbuf, Sbuf, xz_bf, Dp, y_bf);

    // 6. out += y @ W_out  split-K=4, atomic accumulate (out pre-init to x0)
    //    1024 blocks = 4 blk/CU, 8 K-iters each.
    gemm_bf16_kernel<5, false, 64, 64, false><<<dim3(16, 16, 4), 256, 0, stream>>>(
        y_bf, DINNER, WoutT, DINNER, out, DMODEL, DINNER / 4, nullptr, nullptr, 0,
        nullptr, nullptr, nullptr, nullptr);
}

// Round 11
// 233.695 us; speedup vs baseline: 1.0102x; 1.0102x over previous
//
#include <hip/hip_runtime.h>
#include <hip/hip_bf16.h>
#include <math.h>

// Problem constants
#define BATCH 2
#define LSEQ 1024
#define DMODEL 1024
#define DINNER 2048
#define DSTATE 16
#define DTRANK 64
#define NROWS (BATCH * LSEQ)   // 2048 token rows
#define XROW 128               // padded x_proj width (96 -> 128)
#define NC 32                  // scan chunks
#define TCH (LSEQ / NC)        // 32 timesteps per chunk
#define NSPL 16                // x_proj split-K slices

typedef __bf16 bf16;
typedef __attribute__((ext_vector_type(8))) __bf16 bf16x8;
typedef __attribute__((ext_vector_type(2))) __bf16 bf16x2;
typedef __attribute__((ext_vector_type(4))) float floatx4;

// ---------------------------------------------------------------------------
// bf16 MFMA GEMM. TM=128, templated TN/BK. global_load_lds width-16 staging
// with XOR-swizzled K-chunks (8-way LDS conflict -> free 2-way).
// Single-buffered 2-phase loop, BK=64: the proven structure.
// The pipeline is LATENCY-BOUND at small grids (R7: 6% occupancy, 488 GB/s).
// Occupancy levers must be TRAFFIC-NEUTRAL: split-K keeps staged bytes
// constant (R8 -4us, R9 -29us); shrinking TN doubles panel re-reads
// (R10 in_proj TN=64: +10us, ~192->384MB staging). dt TN=64 is exempt
// (A is 256KB). Rejected: dbuf (R1), BK=128 (R2), XCD swizzle (R3),
// grid.sync fusion (R5, +143us), redundant in-GEMM reduction (R7, +26us).
// CONVA (x_proj): A-tile = silu(conv(xz)) inline during staging -- zero
// redundancy since grid.x==1 makes every (y,z) A-slice disjoint.
// MODE 0: C = acc                MODE 1: C = softplus(acc + bias[n])
// MODE 2: C = acc + resid[..]    MODE 4: split-K partial store
// MODE 5: atomicAdd accumulate (C pre-initialized)
// ---------------------------------------------------------------------------
template<int MODE, bool BF16OUT, int TN_, int BK_, bool CONVA>
__global__ __launch_bounds__(256) void gemm_bf16_kernel(
    const bf16* __restrict__ A, int lda,
    const bf16* __restrict__ Bt, int ldb,
    void* __restrict__ Cv, int ldc,
    int Ksplit,
    const float* __restrict__ bias,
    const float* __restrict__ resid, int ldr,
    const bf16* __restrict__ xzc,     // CONVA: xz base (x half)
    const float* __restrict__ cw,     // CONVA: conv_w [DINNER][4]
    const float* __restrict__ cb,     // CONVA: conv_b
    bf16* __restrict__ xcout)         // CONVA: xc side-output
{
    constexpr int TMc  = 128;
    constexpr int CA   = BK_ / 8;                  // chunks per row
    constexpr int ISSA = TMc * BK_ * 2 / 4096;     // 4-KB issues for A
    constexpr int ISSB = TN_ * BK_ * 2 / 4096;
    constexpr int NB   = TN_ / 32;                 // B frags per wave
    constexpr int NH   = BK_ / 32;                 // K halves per iter

    __shared__ __attribute__((aligned(16))) bf16 As[TMc * BK_];
    __shared__ __attribute__((aligned(16))) bf16 Bs[TN_ * BK_];

    const int tid  = threadIdx.x;
    const int lane = tid & 63;
    const int wave = tid >> 6;
    const int l15  = lane & 15;
    const int quad = lane >> 4;
    const int wm   = (wave >> 1) * 64;
    const int wn   = (wave & 1) * (TN_ / 2);

    const int row0 = blockIdx.y * TMc;
    const int col0 = blockIdx.x * TN_;
    const long kbase = (long)blockIdx.z * Ksplit;

    const bf16* gA[ISSA]; bf16* lA[ISSA];
    const bf16* gB[ISSB]; bf16* lB[ISSB];
    if constexpr (!CONVA) {
        #pragma unroll
        for (int i = 0; i < ISSA; ++i) {
            int c = i * 256 + wave * 64 + lane;
            int r = c / CA;
            int kc = (c % CA) ^ (r % CA);
            gA[i] = A + (size_t)(row0 + r) * lda + kbase + kc * 8;
            lA[i] = As + (size_t)(i * 256 + wave * 64) * 8;
        }
    }
    #pragma unroll
    for (int i = 0; i < ISSB; ++i) {
        int c = i * 256 + wave * 64 + lane;
        int r = c / CA;
        int kc = (c % CA) ^ (r % CA);
        gB[i] = Bt + (size_t)(col0 + r) * ldb + kbase + kc * 8;
        lB[i] = Bs + (size_t)(i * 256 + wave * 64) * 8;
    }

    floatx4 acc[4][NB];
    #pragma unroll
    for (int i = 0; i < 4; ++i)
        #pragma unroll
        for (int j = 0; j < NB; ++j)
            acc[i][j] = (floatx4){0.f, 0.f, 0.f, 0.f};

    const int kiters = Ksplit / BK_;
    for (int kk = 0; kk < kiters; ++kk) {
        __syncthreads();
        if constexpr (!CONVA) {
            #pragma unroll
            for (int i = 0; i < ISSA; ++i) {
                __builtin_amdgcn_global_load_lds(
                    (const __attribute__((address_space(1))) void*)gA[i],
                    (__attribute__((address_space(3))) void*)lA[i], 16, 0, 0);
                gA[i] += BK_;
            }
        }
        #pragma unroll
        for (int i = 0; i < ISSB; ++i) {
            __builtin_amdgcn_global_load_lds(
                (const __attribute__((address_space(1))) void*)gB[i],
                (__attribute__((address_space(3))) void*)lB[i], 16, 0, 0);
            gB[i] += BK_;
        }
        if constexpr (CONVA) {
            // A-tile = silu(conv(xz)) per 8-channel chunk; swizzled As write
            // (matches reader (h*4+quad)^(r&7)); side-write xc.
            const int chan0 = (int)kbase + kk * BK_;
            #pragma unroll
            for (int p = 0; p < (TMc * CA) / 256; ++p) {
                int f  = tid + 256 * p;
                int r  = f >> 3;
                int c8 = f & 7;
                int row = row0 + r;
                int l   = row & (LSEQ - 1);
                int ch  = chan0 + c8 * 8;
                const bf16* xp = xzc + (size_t)row * (2 * DINNER) + ch;
                float4 cb0 = *(const float4*)&cb[ch];
                float4 cb1 = *(const float4*)&cb[ch + 4];
                float a[8] = {cb0.x, cb0.y, cb0.z, cb0.w,
                              cb1.x, cb1.y, cb1.z, cb1.w};
                float w0[8], w1[8], w2[8], w3[8];
                #pragma unroll
                for (int i = 0; i < 8; ++i) {
                    float4 w = *(const float4*)&cw[(size_t)(ch + i) * 4];
                    w0[i] = w.x; w1[i] = w.y; w2[i] = w.z; w3[i] = w.w;
                }
                {
                    bf16x8 t = *(const bf16x8*)xp;
                    #pragma unroll
                    for (int i = 0; i < 8; ++i) a[i] += (float)t[i] * w3[i];
                }
                if (l >= 1) {
                    bf16x8 t = *(const bf16x8*)(xp - 2 * DINNER);
                    #pragma unroll
                    for (int i = 0; i < 8; ++i) a[i] += (float)t[i] * w2[i];
                }
                if (l >= 2) {
                    bf16x8 t = *(const bf16x8*)(xp - 4 * DINNER);
                    #pragma unroll
                    for (int i = 0; i < 8; ++i) a[i] += (float)t[i] * w1[i];
                }
                if (l >= 3) {
                    bf16x8 t = *(const bf16x8*)(xp - 6 * DINNER);
                    #pragma unroll
                    for (int i = 0; i < 8; ++i) a[i] += (float)t[i] * w0[i];
                }
                bf16x8 o;
                #pragma unroll
                for (int i = 0; i < 8; ++i) {
                    float s = a[i] / (1.0f + __expf(-a[i]));
                    o[i] = (bf16)s;
                }
                *(bf16x8*)&As[(size_t)r * BK_ + ((c8 ^ (r & 7)) * 8)] = o;
                *(bf16x8*)&xcout[(size_t)row * DINNER + ch] = o;
            }
        }
        __syncthreads();

        #pragma unroll
        for (int h = 0; h < NH; ++h) {
            bf16x8 af[4], bfr[NB];
            #pragma unroll
            for (int i = 0; i < 4; ++i) {
                int r = wm + i * 16 + l15;
                af[i] = *(const bf16x8*)&As[(size_t)r * BK_ +
                          (((h * 4 + quad) ^ (r % CA)) * 8)];
            }
            #pragma unroll
            for (int j = 0; j < NB; ++j) {
                int r = wn + j * 16 + l15;
                bfr[j] = *(const bf16x8*)&Bs[(size_t)r * BK_ +
                           (((h * 4 + quad) ^ (r % CA)) * 8)];
            }
            #pragma unroll
            for (int i = 0; i < 4; ++i)
                #pragma unroll
                for (int j = 0; j < NB; ++j)
                    acc[i][j] = __builtin_amdgcn_mfma_f32_16x16x32_bf16(
                                    af[i], bfr[j], acc[i][j], 0, 0, 0);
        }
    }

    #pragma unroll
    for (int i = 0; i < 4; ++i) {
        #pragma unroll
        for (int j = 0; j < NB; ++j) {
            const int gn = col0 + wn + j * 16 + l15;
            #pragma unroll
            for (int r = 0; r < 4; ++r) {
                const int gm = row0 + wm + i * 16 + quad * 4 + r;
                float v = acc[i][j][r];
                if (MODE == 1) {
                    v += bias[gn];
                    // softplus via raw v_exp/v_log (no OCML): ln(1+e^v)
                    if (v < 20.0f) {
                        float e = __builtin_amdgcn_exp2f(v * 1.4426950408889634f);
                        v = 0.6931471805599453f * __builtin_amdgcn_logf(1.0f + e);
                    }
                }
                if (MODE == 2) v += resid[(size_t)gm * ldr + gn];
                if (MODE == 4) {
                    ((float*)Cv)[(size_t)blockIdx.z * ldr + (size_t)gm * ldc + gn] = v;
                } else if (MODE == 5) {
                    unsafeAtomicAdd((float*)Cv + (size_t)gm * ldc + gn, v);
                } else if (BF16OUT) {
                    ((bf16*)Cv)[(size_t)gm * ldc + gn] = (bf16)v;
                } else {
                    ((float*)Cv)[(size_t)gm * ldc + gn] = v;
                }
            }
        }
    }
}

// ---------------------------------------------------------------------------
// Fused prep: 4 weight transposes (fp32 -> bf16, transposed, zero-pad),
// RMSNorm, and out-init (out <- x0 for the split-K out GEMM).
// ---------------------------------------------------------------------------
__global__ __launch_bounds__(256) void prep_kernel(
    const float* __restrict__ W_in,  bf16* __restrict__ WinT,
    const float* __restrict__ W_x,   bf16* __restrict__ WxT,
    const float* __restrict__ W_dt,  bf16* __restrict__ WdtT,
    const float* __restrict__ W_out, bf16* __restrict__ WoutT,
    const float* __restrict__ x0, const float* __restrict__ norm_w,
    bf16* __restrict__ h, float* __restrict__ out_init)
{
    __shared__ float smem[32 * 33];
    const int bid = blockIdx.x;
    const int tid = threadIdx.x;

    if (bid < 6528) {
        const float* W; bf16* Wt; int K, N, Npad, bx, by;
        if (bid < 4096)      { W = W_in;  Wt = WinT;  K = 1024; N = 4096; Npad = 4096; bx = bid & 127, by = bid >> 7; }
        else if (bid < 4352) { int l = bid - 4096; W = W_x;  Wt = WxT;  K = 2048; N = 96;   Npad = 128;  bx = l & 3,  by = l >> 2; }
        else if (bid < 4480) { int l = bid - 4352; W = W_dt; Wt = WdtT; K = 64;   N = 2048; Npad = 2048; bx = l & 63, by = l >> 6; }
        else                 { int l = bid - 4480; W = W_out;Wt = WoutT;K = 2048; N = 1024; Npad = 1024; bx = l & 31, by = l >> 5; }
        float (*tile)[33] = (float(*)[33])smem;
        const int n0 = bx * 32, k0 = by * 32;
        const int tx = tid & 31, ty = tid >> 5;
        #pragma unroll
        for (int i = 0; i < 32; i += 8) {
            int k = k0 + ty + i, n = n0 + tx;
            tile[ty + i][tx] = (k < K && n < N) ? W[(size_t)k * N + n] : 0.0f;
        }
        __syncthreads();
        #pragma unroll
        for (int i = 0; i < 32; i += 8) {
            int n = n0 + ty + i, k = k0 + tx;
            if (n < Npad && k < K)
                Wt[(size_t)n * K + k] = (bf16)tile[tx][ty + i];
        }
    } else if (bid < 8576) {
        const int row = bid - 6528;
        const float* xr = x0 + (size_t)row * DMODEL;
        float4 v = *(const float4*)(xr + tid * 4);
        float ss = v.x * v.x + v.y * v.y + v.z * v.z + v.w * v.w;
        #pragma unroll
        for (int m = 32; m >= 1; m >>= 1) ss += __shfl_xor(ss, m);
        if ((tid & 63) == 0) smem[tid >> 6] = ss;
        __syncthreads();
        float total = smem[0] + smem[1] + smem[2] + smem[3];
        float scale = rsqrtf(total * (1.0f / DMODEL) + 1e-5f);
        float4 wv = *(const float4*)(norm_w + tid * 4);
        union { bf16 b[4]; uint2 u; } pk;
        pk.b[0] = (bf16)(v.x * scale * wv.x);
        pk.b[1] = (bf16)(v.y * scale * wv.y);
        pk.b[2] = (bf16)(v.z * scale * wv.z);
        pk.b[3] = (bf16)(v.w * scale * wv.w);
        *(uint2*)(h + (size_t)row * DMODEL + tid * 4) = pk.u;
    } else {
        // out <- x0 (8 MB float4 copy)
        size_t idx = ((size_t)(bid - 8576) * 256 + tid) * 4;
        *(float4*)(out_init + idx) = *(const float4*)(x0 + idx);
    }
}

// ---------------------------------------------------------------------------
// Reduce x_proj split-K partials: sum NSPL slices of [NROWS][128].
// cols 0..63 -> dt_bf (bf16), cols 64..95 -> BC fp32 [NROWS][32].
// ---------------------------------------------------------------------------
__global__ __launch_bounds__(256) void xproj_reduce_kernel(
    const float* __restrict__ Pw, bf16* __restrict__ dt,
    float* __restrict__ BC)
{
    int idx = blockIdx.x * 256 + threadIdx.x;   // NROWS*128
    int row = idx >> 7, c = idx & 127;
    float s = 0.0f;
    #pragma unroll
    for (int k = 0; k < NSPL; ++k)
        s += Pw[(size_t)k * NROWS * XROW + idx];
    if (c < 64) dt[(size_t)row * 64 + c] = (bf16)s;
    else if (c < 96) BC[(size_t)row * 32 + (c - 64)] = s;
}

// ---------------------------------------------------------------------------
// Chunked selective scan. Lane = (b, chunk, d); 16 states in registers.
// Phase 1: S = local final state; chunk decay product in log2 domain.
// Combine: chunk-serial fixup. Phase 2: re-run from true init, fused ymod.
// exp path: Ad prefolded by log2(e); raw v_exp_f32 via __builtin_amdgcn_exp2f
// (NOT exp2f -- the OCML wrapper's denormal fixup cost ~18us, R1-R3 lesson).
// ---------------------------------------------------------------------------
template<bool FINAL>
__global__ __launch_bounds__(256) void scan_chunk_kernel(
    const bf16* __restrict__ delta,
    const bf16* __restrict__ xc,
    const float* __restrict__ BC,
    const float* __restrict__ A,
    float* __restrict__ Pbuf,
    float* __restrict__ Sbuf,
    const bf16* __restrict__ xz,
    const float* __restrict__ Dp,
    bf16* __restrict__ ybf)
{
    __shared__ float sBC[TCH][32];
    const int tid   = threadIdx.x;
    const int chunk = blockIdx.x;
    const int d     = blockIdx.y * 256 + tid;
    const int b     = blockIdx.z;
    const int row0  = b * LSEQ + chunk * TCH;

    {
        int t = tid >> 3, c4 = (tid & 7) * 4;
        *(float4*)&sBC[t][c4] = *(const float4*)&BC[(size_t)(row0 + t) * 32 + c4];
    }

    const float L2E = 1.4426950408889634f;
    float Ad[16];
    #pragma unroll
    for (int j = 0; j < 4; ++j) {
        float4 av = *(const float4*)&A[(size_t)d * DSTATE + j * 4];
        Ad[j*4+0] = av.x * L2E; Ad[j*4+1] = av.y * L2E;
        Ad[j*4+2] = av.z * L2E; Ad[j*4+3] = av.w * L2E;
    }

    const size_t psbase = ((size_t)(b * NC + chunk) * DSTATE) * DINNER + d;
    float S[16];
    float sumdv = 0.0f;
    if (FINAL) {
        #pragma unroll
        for (int n = 0; n < 16; ++n) S[n] = Sbuf[psbase + (size_t)n * DINNER];
    } else {
        #pragma unroll
        for (int n = 0; n < 16; ++n) S[n] = 0.0f;
    }
    float Dpd = FINAL ? Dp[d] : 0.0f;

    __syncthreads();

    #pragma unroll 2
    for (int t = 0; t < TCH; ++t) {
        const size_t row = (size_t)(row0 + t);
        float dv = (float)delta[row * DINNER + d];
        float xv = (float)xc[row * DINNER + d];
        float u  = dv * xv;
        float yp[4] = {0.f, 0.f, 0.f, 0.f};
        #pragma unroll
        for (int n = 0; n < 16; ++n) {
            float dA = __builtin_amdgcn_exp2f(dv * Ad[n]);  // bare v_exp_f32
            S[n] = dA * S[n] + u * sBC[t][n];
            if (FINAL) yp[n & 3] += S[n] * sBC[t][16 + n];
        }
        if (FINAL) {
            float y = (yp[0] + yp[1]) + (yp[2] + yp[3]);
            float res = (float)xz[row * (2 * DINNER) + DINNER + d];
            float sres = res / (1.0f + __expf(-res));
            ybf[row * DINNER + d] = (bf16)((y + xv * Dpd) * sres);
        } else {
            sumdv += dv;
        }
    }

    if (!FINAL) {
        #pragma unroll
        for (int n = 0; n < 16; ++n) {
            Pbuf[psbase + (size_t)n * DINNER] = __builtin_amdgcn_exp2f(sumdv * Ad[n]);
            Sbuf[psbase + (size_t)n * DINNER] = S[n];
        }
    }
}

// Per-(b,n,d) serial combine over chunks: Sbuf[k] <- true initial state.
__global__ __launch_bounds__(256) void scan_combine_kernel(
    const float* __restrict__ Pbuf, float* __restrict__ Sbuf)
{
    int gid = blockIdx.x * 256 + threadIdx.x;   // B * 16 * DINNER = 65536
    int b = gid >> 15;
    int nd = gid & 32767;
    float carry = 0.0f;
    for (int k = 0; k < NC; ++k) {
        size_t off = ((size_t)(b * NC + k) << 15) + nd;
        float pk = Pbuf[off];
        float sk = Sbuf[off];
        Sbuf[off] = carry;
        carry = pk * carry + sk;
    }
}

// ---------------------------------------------------------------------------
extern "C" void kernel_launch(void* const* d_in, const int* in_sizes, int n_in,
                              void* d_out, int out_size, void* d_ws, size_t ws_size,
                              hipStream_t stream)
{
    const float* x0     = (const float*)d_in[0];
    const float* norm_w = (const float*)d_in[1];
    const float* W_in   = (const float*)d_in[2];   // [1024,4096]
    const float* conv_w = (const float*)d_in[3];
    const float* conv_b = (const float*)d_in[4];
    const float* W_x    = (const float*)d_in[5];   // [2048,96]
    const float* W_dt   = (const float*)d_in[6];   // [64,2048]
    const float* b_dt   = (const float*)d_in[7];
    const float* A      = (const float*)d_in[8];
    const float* Dp     = (const float*)d_in[9];
    const float* W_out  = (const float*)d_in[10];  // [2048,1024]
    float* out = (float*)d_out;

    // Workspace layout (~84 MB)
    char* p = (char*)d_ws;
    bf16*  xz_bf = (bf16*)p;            p += (size_t)NROWS * 2 * DINNER * 2;        // 16MB
    float* Pw    = (float*)p;           p += (size_t)NSPL * NROWS * XROW * 4;       // 16MB
    float* BC    = (float*)p;           p += (size_t)NROWS * 32 * 4;                // 0.25MB
    bf16*  delta = (bf16*)p;            p += (size_t)NROWS * DINNER * 2;            // 8MB
    float* Pbuf  = (float*)p;           p += (size_t)BATCH * NC * DINNER * 16 * 4;  // 8MB
    float* Sbuf  = (float*)p;           p += (size_t)BATCH * NC * DINNER * 16 * 4;  // 8MB
    bf16*  h_bf  = (bf16*)p;            p += (size_t)NROWS * DMODEL * 2;            // 4MB
    bf16*  xc_bf = (bf16*)p;            p += (size_t)NROWS * DINNER * 2;            // 8MB
    bf16*  y_bf  = (bf16*)p;            p += (size_t)NROWS * DINNER * 2;            // 8MB
    bf16*  WinT  = (bf16*)p;            p += (size_t)(2*DINNER) * DMODEL * 2;       // 8MB
    bf16*  WxT   = (bf16*)p;            p += (size_t)XROW * DINNER * 2;             // 0.5MB
    bf16*  WdtT  = (bf16*)p;            p += (size_t)DINNER * DTRANK * 2;           // 0.25MB
    bf16*  WoutT = (bf16*)p;            p += (size_t)DMODEL * DINNER * 2;           // 4MB
    bf16*  dt_bf = (bf16*)p;            p += (size_t)NROWS * DTRANK * 2;            // 0.25MB

    // 1. Fused prep: weight transposes + RMSNorm + out<-x0 init
    prep_kernel<<<10624, 256, 0, stream>>>(W_in, WinT, W_x, WxT, W_dt, WdtT,
                                           W_out, WoutT, x0, norm_w, h_bf, out);

    // 2. xz = h @ W_in  [2048,1024]x[1024,4096] -> bf16
    //    TN=128 (R9-proven): TN=64 doubled staging traffic, +10us (R10).
    gemm_bf16_kernel<0, true, 128, 64, false><<<dim3(32, 16, 1), 256, 0, stream>>>(
        h_bf, DMODEL, WinT, DMODEL, xz_bf, 2*DINNER, DMODEL, nullptr, nullptr, 0,
        nullptr, nullptr, nullptr, nullptr);

    // 3. x_proj split-K=16 with fused conv+silu A-staging -> Pw slices + xc
    gemm_bf16_kernel<4, false, 128, 64, true><<<dim3(1, 16, NSPL), 256, 0, stream>>>(
        nullptr, 0, WxT, DINNER, Pw, XROW, DINNER / NSPL, nullptr, nullptr, NROWS * XROW,
        xz_bf, conv_w, conv_b, xc_bf);

    // 3b. reduce partials -> dt_bf + BC
    xproj_reduce_kernel<<<(NROWS * XROW) / 256, 256, 0, stream>>>(Pw, dt_bf, BC);

    // 4. delta = softplus(dt @ W_dt + b_dt) -> bf16
    //    TN=64: 512 blocks = 2 blk/CU; 1 K-iter = pure prologue latency,
    //    extra A staging is 256KB (traffic-exempt from the R10 rule).
    gemm_bf16_kernel<1, true, 64, 64, false><<<dim3(32, 16, 1), 256, 0, stream>>>(
        dt_bf, DTRANK, WdtT, DTRANK, delta, DINNER, DTRANK, b_dt, nullptr, 0,
        nullptr, nullptr, nullptr, nullptr);

    // 5. chunked selective scan (+ fused ymod) -> y_bf
    dim3 sgrid(NC, DINNER / 256, BATCH);
    scan_chunk_kernel<false><<<sgrid, 256, 0, stream>>>(
        delta, xc_bf, BC, A, Pbuf, Sbuf, nullptr, nullptr, nullptr);
    scan_combine_kernel<<<(BATCH * DINNER * DSTATE) / 256, 256, 0, stream>>>(Pbuf, Sbuf);
    scan_chunk_kernel<true><<<sgrid, 256, 0, stream>>>(
        delta, xc_bf, BC, A, Pbuf, Sbuf, xz_bf, Dp, y_bf);

    // 6. out += y @ W_out  split-K=4, atomic accumulate (out pre-init to x0)
    //    1024 blocks = 4 blk/CU, 8 K-iters; staged bytes identical to
    //    split-K=2 (split-K is the traffic-neutral occupancy lever).
    gemm_bf16_kernel<5, false, 64, 64, false><<<dim3(16, 16, 4), 256, 0, stream>>>(
        y_bf, DINNER, WoutT, DINNER, out, DMODEL, DINNER / 4, nullptr, nullptr, 0,
        nullptr, nullptr, nullptr, nullptr);
}

// Round 12
// 227.031 us; speedup vs baseline: 1.0399x; 1.0294x over previous
//
#include <hip/hip_runtime.h>
#include <hip/hip_bf16.h>
#include <math.h>

// Problem constants
#define BATCH 2
#define LSEQ 1024
#define DMODEL 1024
#define DINNER 2048
#define DSTATE 16
#define DTRANK 64
#define NROWS (BATCH * LSEQ)   // 2048 token rows
#define XROW 128               // padded x_proj width (96 -> 128)
#define NC 32                  // scan chunks
#define TCH (LSEQ / NC)        // 32 timesteps per chunk
#define NSPL 32                // x_proj split-K slices (R12: 16->32, 2 blk/CU)

typedef __bf16 bf16;
typedef __attribute__((ext_vector_type(8))) __bf16 bf16x8;
typedef __attribute__((ext_vector_type(2))) __bf16 bf16x2;
typedef __attribute__((ext_vector_type(4))) float floatx4;

// ---------------------------------------------------------------------------
// bf16 MFMA GEMM. TM=128, templated TN/BK. global_load_lds width-16 staging
// with XOR-swizzled K-chunks (8-way LDS conflict -> free 2-way).
// Single-buffered 2-phase loop, BK=64: the proven structure.
// The pipeline is LATENCY-BOUND at small grids (R7: 6% occupancy, 488 GB/s).
// Occupancy levers must be TRAFFIC-NEUTRAL: split-K keeps staged bytes
// constant (R8 -4us, R9 -29us); shrinking TN doubles panel re-reads
// (R10 in_proj TN=64: +10us). R11 (dt TN=64 + out sk4): +8us -> reverted;
// out stays sk2, dt stays TN=128. Rejected: dbuf (R1), BK=128 (R2),
// XCD swizzle (R3), grid.sync fusion (R5, +143us), redundant in-GEMM
// reduction (R7, +26us).
// CONVA (x_proj): A-tile = silu(conv(xz)) inline during staging -- zero
// redundancy since grid.x==1 makes every (y,z) A-slice disjoint.
// MODE 0: C = acc                MODE 1: C = softplus(acc + bias[n])
// MODE 2: C = acc + resid[..]    MODE 4: split-K partial store
// MODE 5: atomicAdd accumulate (C pre-initialized)
// ---------------------------------------------------------------------------
template<int MODE, bool BF16OUT, int TN_, int BK_, bool CONVA>
__global__ __launch_bounds__(256) void gemm_bf16_kernel(
    const bf16* __restrict__ A, int lda,
    const bf16* __restrict__ Bt, int ldb,
    void* __restrict__ Cv, int ldc,
    int Ksplit,
    const float* __restrict__ bias,
    const float* __restrict__ resid, int ldr,
    const bf16* __restrict__ xzc,     // CONVA: xz base (x half)
    const float* __restrict__ cw,     // CONVA: conv_w [DINNER][4]
    const float* __restrict__ cb,     // CONVA: conv_b
    bf16* __restrict__ xcout)         // CONVA: xc side-output
{
    constexpr int TMc  = 128;
    constexpr int CA   = BK_ / 8;                  // chunks per row
    constexpr int ISSA = TMc * BK_ * 2 / 4096;     // 4-KB issues for A
    constexpr int ISSB = TN_ * BK_ * 2 / 4096;
    constexpr int NB   = TN_ / 32;                 // B frags per wave
    constexpr int NH   = BK_ / 32;                 // K halves per iter

    __shared__ __attribute__((aligned(16))) bf16 As[TMc * BK_];
    __shared__ __attribute__((aligned(16))) bf16 Bs[TN_ * BK_];

    const int tid  = threadIdx.x;
    const int lane = tid & 63;
    const int wave = tid >> 6;
    const int l15  = lane & 15;
    const int quad = lane >> 4;
    const int wm   = (wave >> 1) * 64;
    const int wn   = (wave & 1) * (TN_ / 2);

    const int row0 = blockIdx.y * TMc;
    const int col0 = blockIdx.x * TN_;
    const long kbase = (long)blockIdx.z * Ksplit;

    const bf16* gA[ISSA]; bf16* lA[ISSA];
    const bf16* gB[ISSB]; bf16* lB[ISSB];
    if constexpr (!CONVA) {
        #pragma unroll
        for (int i = 0; i < ISSA; ++i) {
            int c = i * 256 + wave * 64 + lane;
            int r = c / CA;
            int kc = (c % CA) ^ (r % CA);
            gA[i] = A + (size_t)(row0 + r) * lda + kbase + kc * 8;
            lA[i] = As + (size_t)(i * 256 + wave * 64) * 8;
        }
    }
    #pragma unroll
    for (int i = 0; i < ISSB; ++i) {
        int c = i * 256 + wave * 64 + lane;
        int r = c / CA;
        int kc = (c % CA) ^ (r % CA);
        gB[i] = Bt + (size_t)(col0 + r) * ldb + kbase + kc * 8;
        lB[i] = Bs + (size_t)(i * 256 + wave * 64) * 8;
    }

    floatx4 acc[4][NB];
    #pragma unroll
    for (int i = 0; i < 4; ++i)
        #pragma unroll
        for (int j = 0; j < NB; ++j)
            acc[i][j] = (floatx4){0.f, 0.f, 0.f, 0.f};

    const int kiters = Ksplit / BK_;
    for (int kk = 0; kk < kiters; ++kk) {
        __syncthreads();
        if constexpr (!CONVA) {
            #pragma unroll
            for (int i = 0; i < ISSA; ++i) {
                __builtin_amdgcn_global_load_lds(
                    (const __attribute__((address_space(1))) void*)gA[i],
                    (__attribute__((address_space(3))) void*)lA[i], 16, 0, 0);
                gA[i] += BK_;
            }
        }
        #pragma unroll
        for (int i = 0; i < ISSB; ++i) {
            __builtin_amdgcn_global_load_lds(
                (const __attribute__((address_space(1))) void*)gB[i],
                (__attribute__((address_space(3))) void*)lB[i], 16, 0, 0);
            gB[i] += BK_;
        }
        if constexpr (CONVA) {
            // A-tile = silu(conv(xz)) per 8-channel chunk; swizzled As write
            // (matches reader (h*4+quad)^(r&7)); side-write xc.
            const int chan0 = (int)kbase + kk * BK_;
            #pragma unroll
            for (int p = 0; p < (TMc * CA) / 256; ++p) {
                int f  = tid + 256 * p;
                int r  = f >> 3;
                int c8 = f & 7;
                int row = row0 + r;
                int l   = row & (LSEQ - 1);
                int ch  = chan0 + c8 * 8;
                const bf16* xp = xzc + (size_t)row * (2 * DINNER) + ch;
                float4 cb0 = *(const float4*)&cb[ch];
                float4 cb1 = *(const float4*)&cb[ch + 4];
                float a[8] = {cb0.x, cb0.y, cb0.z, cb0.w,
                              cb1.x, cb1.y, cb1.z, cb1.w};
                float w0[8], w1[8], w2[8], w3[8];
                #pragma unroll
                for (int i = 0; i < 8; ++i) {
                    float4 w = *(const float4*)&cw[(size_t)(ch + i) * 4];
                    w0[i] = w.x; w1[i] = w.y; w2[i] = w.z; w3[i] = w.w;
                }
                {
                    bf16x8 t = *(const bf16x8*)xp;
                    #pragma unroll
                    for (int i = 0; i < 8; ++i) a[i] += (float)t[i] * w3[i];
                }
                if (l >= 1) {
                    bf16x8 t = *(const bf16x8*)(xp - 2 * DINNER);
                    #pragma unroll
                    for (int i = 0; i < 8; ++i) a[i] += (float)t[i] * w2[i];
                }
                if (l >= 2) {
                    bf16x8 t = *(const bf16x8*)(xp - 4 * DINNER);
                    #pragma unroll
                    for (int i = 0; i < 8; ++i) a[i] += (float)t[i] * w1[i];
                }
                if (l >= 3) {
                    bf16x8 t = *(const bf16x8*)(xp - 6 * DINNER);
                    #pragma unroll
                    for (int i = 0; i < 8; ++i) a[i] += (float)t[i] * w0[i];
                }
                bf16x8 o;
                #pragma unroll
                for (int i = 0; i < 8; ++i) {
                    float s = a[i] / (1.0f + __expf(-a[i]));
                    o[i] = (bf16)s;
                }
                *(bf16x8*)&As[(size_t)r * BK_ + ((c8 ^ (r & 7)) * 8)] = o;
                *(bf16x8*)&xcout[(size_t)row * DINNER + ch] = o;
            }
        }
        __syncthreads();

        #pragma unroll
        for (int h = 0; h < NH; ++h) {
            bf16x8 af[4], bfr[NB];
            #pragma unroll
            for (int i = 0; i < 4; ++i) {
                int r = wm + i * 16 + l15;
                af[i] = *(const bf16x8*)&As[(size_t)r * BK_ +
                          (((h * 4 + quad) ^ (r % CA)) * 8)];
            }
            #pragma unroll
            for (int j = 0; j < NB; ++j) {
                int r = wn + j * 16 + l15;
                bfr[j] = *(const bf16x8*)&Bs[(size_t)r * BK_ +
                           (((h * 4 + quad) ^ (r % CA)) * 8)];
            }
            #pragma unroll
            for (int i = 0; i < 4; ++i)
                #pragma unroll
                for (int j = 0; j < NB; ++j)
                    acc[i][j] = __builtin_amdgcn_mfma_f32_16x16x32_bf16(
                                    af[i], bfr[j], acc[i][j], 0, 0, 0);
        }
    }

    #pragma unroll
    for (int i = 0; i < 4; ++i) {
        #pragma unroll
        for (int j = 0; j < NB; ++j) {
            const int gn = col0 + wn + j * 16 + l15;
            #pragma unroll
            for (int r = 0; r < 4; ++r) {
                const int gm = row0 + wm + i * 16 + quad * 4 + r;
                float v = acc[i][j][r];
                if (MODE == 1) {
                    v += bias[gn];
                    // softplus via raw v_exp/v_log (no OCML): ln(1+e^v)
                    if (v < 20.0f) {
                        float e = __builtin_amdgcn_exp2f(v * 1.4426950408889634f);
                        v = 0.6931471805599453f * __builtin_amdgcn_logf(1.0f + e);
                    }
                }
                if (MODE == 2) v += resid[(size_t)gm * ldr + gn];
                if (MODE == 4) {
                    ((float*)Cv)[(size_t)blockIdx.z * ldr + (size_t)gm * ldc + gn] = v;
                } else if (MODE == 5) {
                    unsafeAtomicAdd((float*)Cv + (size_t)gm * ldc + gn, v);
                } else if (BF16OUT) {
                    ((bf16*)Cv)[(size_t)gm * ldc + gn] = (bf16)v;
                } else {
                    ((float*)Cv)[(size_t)gm * ldc + gn] = v;
                }
            }
        }
    }
}

// ---------------------------------------------------------------------------
// Fused prep: 4 weight transposes (fp32 -> bf16, transposed, zero-pad),
// RMSNorm, and out-init (out <- x0 for the split-K out GEMM).
// ---------------------------------------------------------------------------
__global__ __launch_bounds__(256) void prep_kernel(
    const float* __restrict__ W_in,  bf16* __restrict__ WinT,
    const float* __restrict__ W_x,   bf16* __restrict__ WxT,
    const float* __restrict__ W_dt,  bf16* __restrict__ WdtT,
    const float* __restrict__ W_out, bf16* __restrict__ WoutT,
    const float* __restrict__ x0, const float* __restrict__ norm_w,
    bf16* __restrict__ h, float* __restrict__ out_init)
{
    __shared__ float smem[32 * 33];
    const int bid = blockIdx.x;
    const int tid = threadIdx.x;

    if (bid < 6528) {
        const float* W; bf16* Wt; int K, N, Npad, bx, by;
        if (bid < 4096)      { W = W_in;  Wt = WinT;  K = 1024; N = 4096; Npad = 4096; bx = bid & 127, by = bid >> 7; }
        else if (bid < 4352) { int l = bid - 4096; W = W_x;  Wt = WxT;  K = 2048; N = 96;   Npad = 128;  bx = l & 3,  by = l >> 2; }
        else if (bid < 4480) { int l = bid - 4352; W = W_dt; Wt = WdtT; K = 64;   N = 2048; Npad = 2048; bx = l & 63, by = l >> 6; }
        else                 { int l = bid - 4480; W = W_out;Wt = WoutT;K = 2048; N = 1024; Npad = 1024; bx = l & 31, by = l >> 5; }
        float (*tile)[33] = (float(*)[33])smem;
        const int n0 = bx * 32, k0 = by * 32;
        const int tx = tid & 31, ty = tid >> 5;
        #pragma unroll
        for (int i = 0; i < 32; i += 8) {
            int k = k0 + ty + i, n = n0 + tx;
            tile[ty + i][tx] = (k < K && n < N) ? W[(size_t)k * N + n] : 0.0f;
        }
        __syncthreads();
        #pragma unroll
        for (int i = 0; i < 32; i += 8) {
            int n = n0 + ty + i, k = k0 + tx;
            if (n < Npad && k < K)
                Wt[(size_t)n * K + k] = (bf16)tile[tx][ty + i];
        }
    } else if (bid < 8576) {
        const int row = bid - 6528;
        const float* xr = x0 + (size_t)row * DMODEL;
        float4 v = *(const float4*)(xr + tid * 4);
        float ss = v.x * v.x + v.y * v.y + v.z * v.z + v.w * v.w;
        #pragma unroll
        for (int m = 32; m >= 1; m >>= 1) ss += __shfl_xor(ss, m);
        if ((tid & 63) == 0) smem[tid >> 6] = ss;
        __syncthreads();
        float total = smem[0] + smem[1] + smem[2] + smem[3];
        float scale = rsqrtf(total * (1.0f / DMODEL) + 1e-5f);
        float4 wv = *(const float4*)(norm_w + tid * 4);
        union { bf16 b[4]; uint2 u; } pk;
        pk.b[0] = (bf16)(v.x * scale * wv.x);
        pk.b[1] = (bf16)(v.y * scale * wv.y);
        pk.b[2] = (bf16)(v.z * scale * wv.z);
        pk.b[3] = (bf16)(v.w * scale * wv.w);
        *(uint2*)(h + (size_t)row * DMODEL + tid * 4) = pk.u;
    } else {
        // out <- x0 (8 MB float4 copy)
        size_t idx = ((size_t)(bid - 8576) * 256 + tid) * 4;
        *(float4*)(out_init + idx) = *(const float4*)(x0 + idx);
    }
}

// ---------------------------------------------------------------------------
// Reduce x_proj split-K partials: sum NSPL slices of [NROWS][128].
// cols 0..63 -> dt_bf (bf16), cols 64..95 -> BC fp32 [NROWS][32].
// ---------------------------------------------------------------------------
__global__ __launch_bounds__(256) void xproj_reduce_kernel(
    const float* __restrict__ Pw, bf16* __restrict__ dt,
    float* __restrict__ BC)
{
    int idx = blockIdx.x * 256 + threadIdx.x;   // NROWS*128
    int row = idx >> 7, c = idx & 127;
    float s = 0.0f;
    #pragma unroll
    for (int k = 0; k < NSPL; ++k)
        s += Pw[(size_t)k * NROWS * XROW + idx];
    if (c < 64) dt[(size_t)row * 64 + c] = (bf16)s;
    else if (c < 96) BC[(size_t)row * 32 + (c - 64)] = s;
}

// ---------------------------------------------------------------------------
// Chunked selective scan. Lane = (b, chunk, d); 16 states in registers.
// Phase 1: S = local final state; chunk decay product in log2 domain.
// Combine: chunk-serial fixup. Phase 2: re-run from true init, fused ymod.
// exp path: Ad prefolded by log2(e); raw v_exp_f32 via __builtin_amdgcn_exp2f
// (NOT exp2f -- the OCML wrapper's denormal fixup cost ~18us, R1-R3 lesson).
// ---------------------------------------------------------------------------
template<bool FINAL>
__global__ __launch_bounds__(256) void scan_chunk_kernel(
    const bf16* __restrict__ delta,
    const bf16* __restrict__ xc,
    const float* __restrict__ BC,
    const float* __restrict__ A,
    float* __restrict__ Pbuf,
    float* __restrict__ Sbuf,
    const bf16* __restrict__ xz,
    const float* __restrict__ Dp,
    bf16* __restrict__ ybf)
{
    __shared__ float sBC[TCH][32];
    const int tid   = threadIdx.x;
    const int chunk = blockIdx.x;
    const int d     = blockIdx.y * 256 + tid;
    const int b     = blockIdx.z;
    const int row0  = b * LSEQ + chunk * TCH;

    {
        int t = tid >> 3, c4 = (tid & 7) * 4;
        *(float4*)&sBC[t][c4] = *(const float4*)&BC[(size_t)(row0 + t) * 32 + c4];
    }

    const float L2E = 1.4426950408889634f;
    float Ad[16];
    #pragma unroll
    for (int j = 0; j < 4; ++j) {
        float4 av = *(const float4*)&A[(size_t)d * DSTATE + j * 4];
        Ad[j*4+0] = av.x * L2E; Ad[j*4+1] = av.y * L2E;
        Ad[j*4+2] = av.z * L2E; Ad[j*4+3] = av.w * L2E;
    }

    const size_t psbase = ((size_t)(b * NC + chunk) * DSTATE) * DINNER + d;
    float S[16];
    float sumdv = 0.0f;
    if (FINAL) {
        #pragma unroll
        for (int n = 0; n < 16; ++n) S[n] = Sbuf[psbase + (size_t)n * DINNER];
    } else {
        #pragma unroll
        for (int n = 0; n < 16; ++n) S[n] = 0.0f;
    }
    float Dpd = FINAL ? Dp[d] : 0.0f;

    __syncthreads();

    #pragma unroll 2
    for (int t = 0; t < TCH; ++t) {
        const size_t row = (size_t)(row0 + t);
        float dv = (float)delta[row * DINNER + d];
        float xv = (float)xc[row * DINNER + d];
        float u  = dv * xv;
        float yp[4] = {0.f, 0.f, 0.f, 0.f};
        #pragma unroll
        for (int n = 0; n < 16; ++n) {
            float dA = __builtin_amdgcn_exp2f(dv * Ad[n]);  // bare v_exp_f32
            S[n] = dA * S[n] + u * sBC[t][n];
            if (FINAL) yp[n & 3] += S[n] * sBC[t][16 + n];
        }
        if (FINAL) {
            float y = (yp[0] + yp[1]) + (yp[2] + yp[3]);
            float res = (float)xz[row * (2 * DINNER) + DINNER + d];
            float sres = res / (1.0f + __expf(-res));
            ybf[row * DINNER + d] = (bf16)((y + xv * Dpd) * sres);
        } else {
            sumdv += dv;
        }
    }

    if (!FINAL) {
        #pragma unroll
        for (int n = 0; n < 16; ++n) {
            Pbuf[psbase + (size_t)n * DINNER] = __builtin_amdgcn_exp2f(sumdv * Ad[n]);
            Sbuf[psbase + (size_t)n * DINNER] = S[n];
        }
    }
}

// Per-(b,n,d) serial combine over chunks: Sbuf[k] <- true initial state.
__global__ __launch_bounds__(256) void scan_combine_kernel(
    const float* __restrict__ Pbuf, float* __restrict__ Sbuf)
{
    int gid = blockIdx.x * 256 + threadIdx.x;   // B * 16 * DINNER = 65536
    int b = gid >> 15;
    int nd = gid & 32767;
    float carry = 0.0f;
    for (int k = 0; k < NC; ++k) {
        size_t off = ((size_t)(b * NC + k) << 15) + nd;
        float pk = Pbuf[off];
        float sk = Sbuf[off];
        Sbuf[off] = carry;
        carry = pk * carry + sk;
    }
}

// ---------------------------------------------------------------------------
extern "C" void kernel_launch(void* const* d_in, const int* in_sizes, int n_in,
                              void* d_out, int out_size, void* d_ws, size_t ws_size,
                              hipStream_t stream)
{
    const float* x0     = (const float*)d_in[0];
    const float* norm_w = (const float*)d_in[1];
    const float* W_in   = (const float*)d_in[2];   // [1024,4096]
    const float* conv_w = (const float*)d_in[3];
    const float* conv_b = (const float*)d_in[4];
    const float* W_x    = (const float*)d_in[5];   // [2048,96]
    const float* W_dt   = (const float*)d_in[6];   // [64,2048]
    const float* b_dt   = (const float*)d_in[7];
    const float* A      = (const float*)d_in[8];
    const float* Dp     = (const float*)d_in[9];
    const float* W_out  = (const float*)d_in[10];  // [2048,1024]
    float* out = (float*)d_out;

    // Workspace layout (~100 MB)
    char* p = (char*)d_ws;
    bf16*  xz_bf = (bf16*)p;            p += (size_t)NROWS * 2 * DINNER * 2;        // 16MB
    float* Pw    = (float*)p;           p += (size_t)NSPL * NROWS * XROW * 4;       // 32MB
    float* BC    = (float*)p;           p += (size_t)NROWS * 32 * 4;                // 0.25MB
    bf16*  delta = (bf16*)p;            p += (size_t)NROWS * DINNER * 2;            // 8MB
    float* Pbuf  = (float*)p;           p += (size_t)BATCH * NC * DINNER * 16 * 4;  // 8MB
    float* Sbuf  = (float*)p;           p += (size_t)BATCH * NC * DINNER * 16 * 4;  // 8MB
    bf16*  h_bf  = (bf16*)p;            p += (size_t)NROWS * DMODEL * 2;            // 4MB
    bf16*  xc_bf = (bf16*)p;            p += (size_t)NROWS * DINNER * 2;            // 8MB
    bf16*  y_bf  = (bf16*)p;            p += (size_t)NROWS * DINNER * 2;            // 8MB
    bf16*  WinT  = (bf16*)p;            p += (size_t)(2*DINNER) * DMODEL * 2;       // 8MB
    bf16*  WxT   = (bf16*)p;            p += (size_t)XROW * DINNER * 2;             // 0.5MB
    bf16*  WdtT  = (bf16*)p;            p += (size_t)DINNER * DTRANK * 2;           // 0.25MB
    bf16*  WoutT = (bf16*)p;            p += (size_t)DMODEL * DINNER * 2;           // 4MB
    bf16*  dt_bf = (bf16*)p;            p += (size_t)NROWS * DTRANK * 2;            // 0.25MB

    // 1. Fused prep: weight transposes + RMSNorm + out<-x0 init
    prep_kernel<<<10624, 256, 0, stream>>>(W_in, WinT, W_x, WxT, W_dt, WdtT,
                                           W_out, WoutT, x0, norm_w, h_bf, out);

    // 2. xz = h @ W_in  [2048,1024]x[1024,4096] -> bf16  (R9-proven TN=128)
    gemm_bf16_kernel<0, true, 128, 64, false><<<dim3(32, 16, 1), 256, 0, stream>>>(
        h_bf, DMODEL, WinT, DMODEL, xz_bf, 2*DINNER, DMODEL, nullptr, nullptr, 0,
        nullptr, nullptr, nullptr, nullptr);

    // 3. x_proj split-K=32 with fused conv+silu A-staging -> Pw slices + xc
    //    R12 probe: NSPL 16->32 = 512 blocks = 2 blk/CU (was 1). B staging
    //    and conv work invariant in NSPL; only Pw partial traffic grows.
    gemm_bf16_kernel<4, false, 128, 64, true><<<dim3(1, 16, NSPL), 256, 0, stream>>>(
        nullptr, 0, WxT, DINNER, Pw, XROW, DINNER / NSPL, nullptr, nullptr, NROWS * XROW,
        xz_bf, conv_w, conv_b, xc_bf);

    // 3b. reduce partials -> dt_bf + BC
    xproj_reduce_kernel<<<(NROWS * XROW) / 256, 256, 0, stream>>>(Pw, dt_bf, BC);

    // 4. delta = softplus(dt @ W_dt + b_dt) -> bf16  (R9-proven TN=128)
    gemm_bf16_kernel<1, true, 128, 64, false><<<dim3(16, 16, 1), 256, 0, stream>>>(
        dt_bf, DTRANK, WdtT, DTRANK, delta, DINNER, DTRANK, b_dt, nullptr, 0,
        nullptr, nullptr, nullptr, nullptr);

    // 5. chunked selective scan (+ fused ymod) -> y_bf
    dim3 sgrid(NC, DINNER / 256, BATCH);
    scan_chunk_kernel<false><<<sgrid, 256, 0, stream>>>(
        delta, xc_bf, BC, A, Pbuf, Sbuf, nullptr, nullptr, nullptr);
    scan_combine_kernel<<<(BATCH * DINNER * DSTATE) / 256, 256, 0, stream>>>(Pbuf, Sbuf);
    scan_chunk_kernel<true><<<sgrid, 256, 0, stream>>>(
        delta, xc_bf, BC, A, Pbuf, Sbuf, xz_bf, Dp, y_bf);

    // 6. out += y @ W_out  split-K=2, atomic accumulate (R9-proven sk2)
    gemm_bf16_kernel<5, false, 64, 64, false><<<dim3(16, 16, 2), 256, 0, stream>>>(
        y_bf, DINNER, WoutT, DINNER, out, DMODEL, DINNER / 2, nullptr, nullptr, 0,
        nullptr, nullptr, nullptr, nullptr);
}

// Round 13
// 223.067 us; speedup vs baseline: 1.0584x; 1.0178x over previous
//
#include <hip/hip_runtime.h>
#include <hip/hip_bf16.h>
#include <math.h>

// Problem constants
#define BATCH 2
#define LSEQ 1024
#define DMODEL 1024
#define DINNER 2048
#define DSTATE 16
#define DTRANK 64
#define NROWS (BATCH * LSEQ)   // 2048 token rows
#define XROW 128               // padded x_proj width (96 -> 128)
#define NC 32                  // scan chunks
#define TCH (LSEQ / NC)        // 32 timesteps per chunk
#define NSPL 16                // x_proj split-K slices (R9-proven; 32 was +1.3us)

typedef __bf16 bf16;
typedef __attribute__((ext_vector_type(8))) __bf16 bf16x8;
typedef __attribute__((ext_vector_type(2))) __bf16 bf16x2;
typedef __attribute__((ext_vector_type(4))) float floatx4;

// ---------------------------------------------------------------------------
// bf16 MFMA GEMM. TM=128, templated TN/BK. global_load_lds width-16 staging
// with XOR-swizzled K-chunks (8-way LDS conflict -> free 2-way).
// Single-buffered 2-phase loop, BK=64: the proven structure.
//
// SESSION LEDGER (final config = R9, 225.7us; baseline was 259.7):
//   WINS: raw v_exp_f32 not OCML exp2f (R4, the R1-R3 +18us tax);
//         split-K=2 out GEMM + fp32 atomics (R8, -4us);
//         conv+silu fused into x_proj A-staging (R9, -29us).
//   NON-WINS (all reverted): explicit LDS dbuf (R1), BK=128 (R2),
//         XCD swizzle (R3, L3-resident), grid.sync scan fusion (R5, +143us),
//         redundant in-GEMM reduction (R7, +26us), in_proj TN=64 (R10,
//         +10us: TN-shrink doubles panel staging), dt TN=64 + out sk4
//         (R11, +8us: atomic count scales cost), NSPL=32 (R12, +1.3us).
//   RULE: occupancy levers pay ONLY when traffic-neutral and atomic-light.
//
// CONVA (x_proj): A-tile = silu(conv(xz)) inline during staging -- zero
// redundancy since grid.x==1 makes every (y,z) A-slice disjoint.
// MODE 0: C = acc                MODE 1: C = softplus(acc + bias[n])
// MODE 2: C = acc + resid[..]    MODE 4: split-K partial store
// MODE 5: atomicAdd accumulate (C pre-initialized)
// ---------------------------------------------------------------------------
template<int MODE, bool BF16OUT, int TN_, int BK_, bool CONVA>
__global__ __launch_bounds__(256) void gemm_bf16_kernel(
    const bf16* __restrict__ A, int lda,
    const bf16* __restrict__ Bt, int ldb,
    void* __restrict__ Cv, int ldc,
    int Ksplit,
    const float* __restrict__ bias,
    const float* __restrict__ resid, int ldr,
    const bf16* __restrict__ xzc,     // CONVA: xz base (x half)
    const float* __restrict__ cw,     // CONVA: conv_w [DINNER][4]
    const float* __restrict__ cb,     // CONVA: conv_b
    bf16* __restrict__ xcout)         // CONVA: xc side-output
{
    constexpr int TMc  = 128;
    constexpr int CA   = BK_ / 8;                  // chunks per row
    constexpr int ISSA = TMc * BK_ * 2 / 4096;     // 4-KB issues for A
    constexpr int ISSB = TN_ * BK_ * 2 / 4096;
    constexpr int NB   = TN_ / 32;                 // B frags per wave
    constexpr int NH   = BK_ / 32;                 // K halves per iter

    __shared__ __attribute__((aligned(16))) bf16 As[TMc * BK_];
    __shared__ __attribute__((aligned(16))) bf16 Bs[TN_ * BK_];

    const int tid  = threadIdx.x;
    const int lane = tid & 63;
    const int wave = tid >> 6;
    const int l15  = lane & 15;
    const int quad = lane >> 4;
    const int wm   = (wave >> 1) * 64;
    const int wn   = (wave & 1) * (TN_ / 2);

    const int row0 = blockIdx.y * TMc;
    const int col0 = blockIdx.x * TN_;
    const long kbase = (long)blockIdx.z * Ksplit;

    const bf16* gA[ISSA]; bf16* lA[ISSA];
    const bf16* gB[ISSB]; bf16* lB[ISSB];
    if constexpr (!CONVA) {
        #pragma unroll
        for (int i = 0; i < ISSA; ++i) {
            int c = i * 256 + wave * 64 + lane;
            int r = c / CA;
            int kc = (c % CA) ^ (r % CA);
            gA[i] = A + (size_t)(row0 + r) * lda + kbase + kc * 8;
            lA[i] = As + (size_t)(i * 256 + wave * 64) * 8;
        }
    }
    #pragma unroll
    for (int i = 0; i < ISSB; ++i) {
        int c = i * 256 + wave * 64 + lane;
        int r = c / CA;
        int kc = (c % CA) ^ (r % CA);
        gB[i] = Bt + (size_t)(col0 + r) * ldb + kbase + kc * 8;
        lB[i] = Bs + (size_t)(i * 256 + wave * 64) * 8;
    }

    floatx4 acc[4][NB];
    #pragma unroll
    for (int i = 0; i < 4; ++i)
        #pragma unroll
        for (int j = 0; j < NB; ++j)
            acc[i][j] = (floatx4){0.f, 0.f, 0.f, 0.f};

    const int kiters = Ksplit / BK_;
    for (int kk = 0; kk < kiters; ++kk) {
        __syncthreads();
        if constexpr (!CONVA) {
            #pragma unroll
            for (int i = 0; i < ISSA; ++i) {
                __builtin_amdgcn_global_load_lds(
                    (const __attribute__((address_space(1))) void*)gA[i],
                    (__attribute__((address_space(3))) void*)lA[i], 16, 0, 0);
                gA[i] += BK_;
            }
        }
        #pragma unroll
        for (int i = 0; i < ISSB; ++i) {
            __builtin_amdgcn_global_load_lds(
                (const __attribute__((address_space(1))) void*)gB[i],
                (__attribute__((address_space(3))) void*)lB[i], 16, 0, 0);
            gB[i] += BK_;
        }
        if constexpr (CONVA) {
            // A-tile = silu(conv(xz)) per 8-channel chunk; swizzled As write
            // (matches reader (h*4+quad)^(r&7)); side-write xc.
            const int chan0 = (int)kbase + kk * BK_;
            #pragma unroll
            for (int p = 0; p < (TMc * CA) / 256; ++p) {
                int f  = tid + 256 * p;
                int r  = f >> 3;
                int c8 = f & 7;
                int row = row0 + r;
                int l   = row & (LSEQ - 1);
                int ch  = chan0 + c8 * 8;
                const bf16* xp = xzc + (size_t)row * (2 * DINNER) + ch;
                float4 cb0 = *(const float4*)&cb[ch];
                float4 cb1 = *(const float4*)&cb[ch + 4];
                float a[8] = {cb0.x, cb0.y, cb0.z, cb0.w,
                              cb1.x, cb1.y, cb1.z, cb1.w};
                float w0[8], w1[8], w2[8], w3[8];
                #pragma unroll
                for (int i = 0; i < 8; ++i) {
                    float4 w = *(const float4*)&cw[(size_t)(ch + i) * 4];
                    w0[i] = w.x; w1[i] = w.y; w2[i] = w.z; w3[i] = w.w;
                }
                {
                    bf16x8 t = *(const bf16x8*)xp;
                    #pragma unroll
                    for (int i = 0; i < 8; ++i) a[i] += (float)t[i] * w3[i];
                }
                if (l >= 1) {
                    bf16x8 t = *(const bf16x8*)(xp - 2 * DINNER);
                    #pragma unroll
                    for (int i = 0; i < 8; ++i) a[i] += (float)t[i] * w2[i];
                }
                if (l >= 2) {
                    bf16x8 t = *(const bf16x8*)(xp - 4 * DINNER);
                    #pragma unroll
                    for (int i = 0; i < 8; ++i) a[i] += (float)t[i] * w1[i];
                }
                if (l >= 3) {
                    bf16x8 t = *(const bf16x8*)(xp - 6 * DINNER);
                    #pragma unroll
                    for (int i = 0; i < 8; ++i) a[i] += (float)t[i] * w0[i];
                }
                bf16x8 o;
                #pragma unroll
                for (int i = 0; i < 8; ++i) {
                    float s = a[i] / (1.0f + __expf(-a[i]));
                    o[i] = (bf16)s;
                }
                *(bf16x8*)&As[(size_t)r * BK_ + ((c8 ^ (r & 7)) * 8)] = o;
                *(bf16x8*)&xcout[(size_t)row * DINNER + ch] = o;
            }
        }
        __syncthreads();

        #pragma unroll
        for (int h = 0; h < NH; ++h) {
            bf16x8 af[4], bfr[NB];
            #pragma unroll
            for (int i = 0; i < 4; ++i) {
                int r = wm + i * 16 + l15;
                af[i] = *(const bf16x8*)&As[(size_t)r * BK_ +
                          (((h * 4 + quad) ^ (r % CA)) * 8)];
            }
            #pragma unroll
            for (int j = 0; j < NB; ++j) {
                int r = wn + j * 16 + l15;
                bfr[j] = *(const bf16x8*)&Bs[(size_t)r * BK_ +
                           (((h * 4 + quad) ^ (r % CA)) * 8)];
            }
            #pragma unroll
            for (int i = 0; i < 4; ++i)
                #pragma unroll
                for (int j = 0; j < NB; ++j)
                    acc[i][j] = __builtin_amdgcn_mfma_f32_16x16x32_bf16(
                                    af[i], bfr[j], acc[i][j], 0, 0, 0);
        }
    }

    #pragma unroll
    for (int i = 0; i < 4; ++i) {
        #pragma unroll
        for (int j = 0; j < NB; ++j) {
            const int gn = col0 + wn + j * 16 + l15;
            #pragma unroll
            for (int r = 0; r < 4; ++r) {
                const int gm = row0 + wm + i * 16 + quad * 4 + r;
                float v = acc[i][j][r];
                if (MODE == 1) {
                    v += bias[gn];
                    // softplus via raw v_exp/v_log (no OCML): ln(1+e^v)
                    if (v < 20.0f) {
                        float e = __builtin_amdgcn_exp2f(v * 1.4426950408889634f);
                        v = 0.6931471805599453f * __builtin_amdgcn_logf(1.0f + e);
                    }
                }
                if (MODE == 2) v += resid[(size_t)gm * ldr + gn];
                if (MODE == 4) {
                    ((float*)Cv)[(size_t)blockIdx.z * ldr + (size_t)gm * ldc + gn] = v;
                } else if (MODE == 5) {
                    unsafeAtomicAdd((float*)Cv + (size_t)gm * ldc + gn, v);
                } else if (BF16OUT) {
                    ((bf16*)Cv)[(size_t)gm * ldc + gn] = (bf16)v;
                } else {
                    ((float*)Cv)[(size_t)gm * ldc + gn] = v;
                }
            }
        }
    }
}

// ---------------------------------------------------------------------------
// Fused prep: 4 weight transposes (fp32 -> bf16, transposed, zero-pad),
// RMSNorm, and out-init (out <- x0 for the split-K out GEMM).
// ---------------------------------------------------------------------------
__global__ __launch_bounds__(256) void prep_kernel(
    const float* __restrict__ W_in,  bf16* __restrict__ WinT,
    const float* __restrict__ W_x,   bf16* __restrict__ WxT,
    const float* __restrict__ W_dt,  bf16* __restrict__ WdtT,
    const float* __restrict__ W_out, bf16* __restrict__ WoutT,
    const float* __restrict__ x0, const float* __restrict__ norm_w,
    bf16* __restrict__ h, float* __restrict__ out_init)
{
    __shared__ float smem[32 * 33];
    const int bid = blockIdx.x;
    const int tid = threadIdx.x;

    if (bid < 6528) {
        const float* W; bf16* Wt; int K, N, Npad, bx, by;
        if (bid < 4096)      { W = W_in;  Wt = WinT;  K = 1024; N = 4096; Npad = 4096; bx = bid & 127, by = bid >> 7; }
        else if (bid < 4352) { int l = bid - 4096; W = W_x;  Wt = WxT;  K = 2048; N = 96;   Npad = 128;  bx = l & 3,  by = l >> 2; }
        else if (bid < 4480) { int l = bid - 4352; W = W_dt; Wt = WdtT; K = 64;   N = 2048; Npad = 2048; bx = l & 63, by = l >> 6; }
        else                 { int l = bid - 4480; W = W_out;Wt = WoutT;K = 2048; N = 1024; Npad = 1024; bx = l & 31, by = l >> 5; }
        float (*tile)[33] = (float(*)[33])smem;
        const int n0 = bx * 32, k0 = by * 32;
        const int tx = tid & 31, ty = tid >> 5;
        #pragma unroll
        for (int i = 0; i < 32; i += 8) {
            int k = k0 + ty + i, n = n0 + tx;
            tile[ty + i][tx] = (k < K && n < N) ? W[(size_t)k * N + n] : 0.0f;
        }
        __syncthreads();
        #pragma unroll
        for (int i = 0; i < 32; i += 8) {
            int n = n0 + ty + i, k = k0 + tx;
            if (n < Npad && k < K)
                Wt[(size_t)n * K + k] = (bf16)tile[tx][ty + i];
        }
    } else if (bid < 8576) {
        const int row = bid - 6528;
        const float* xr = x0 + (size_t)row * DMODEL;
        float4 v = *(const float4*)(xr + tid * 4);
        float ss = v.x * v.x + v.y * v.y + v.z * v.z + v.w * v.w;
        #pragma unroll
        for (int m = 32; m >= 1; m >>= 1) ss += __shfl_xor(ss, m);
        if ((tid & 63) == 0) smem[tid >> 6] = ss;
        __syncthreads();
        float total = smem[0] + smem[1] + smem[2] + smem[3];
        float scale = rsqrtf(total * (1.0f / DMODEL) + 1e-5f);
        float4 wv = *(const float4*)(norm_w + tid * 4);
        union { bf16 b[4]; uint2 u; } pk;
        pk.b[0] = (bf16)(v.x * scale * wv.x);
        pk.b[1] = (bf16)(v.y * scale * wv.y);
        pk.b[2] = (bf16)(v.z * scale * wv.z);
        pk.b[3] = (bf16)(v.w * scale * wv.w);
        *(uint2*)(h + (size_t)row * DMODEL + tid * 4) = pk.u;
    } else {
        // out <- x0 (8 MB float4 copy)
        size_t idx = ((size_t)(bid - 8576) * 256 + tid) * 4;
        *(float4*)(out_init + idx) = *(const float4*)(x0 + idx);
    }
}

// ---------------------------------------------------------------------------
// Reduce x_proj split-K partials: sum NSPL slices of [NROWS][128].
// cols 0..63 -> dt_bf (bf16), cols 64..95 -> BC fp32 [NROWS][32].
// ---------------------------------------------------------------------------
__global__ __launch_bounds__(256) void xproj_reduce_kernel(
    const float* __restrict__ Pw, bf16* __restrict__ dt,
    float* __restrict__ BC)
{
    int idx = blockIdx.x * 256 + threadIdx.x;   // NROWS*128
    int row = idx >> 7, c = idx & 127;
    float s = 0.0f;
    #pragma unroll
    for (int k = 0; k < NSPL; ++k)
        s += Pw[(size_t)k * NROWS * XROW + idx];
    if (c < 64) dt[(size_t)row * 64 + c] = (bf16)s;
    else if (c < 96) BC[(size_t)row * 32 + (c - 64)] = s;
}

// ---------------------------------------------------------------------------
// Chunked selective scan. Lane = (b, chunk, d); 16 states in registers.
// Phase 1: S = local final state; chunk decay product in log2 domain.
// Combine: chunk-serial fixup. Phase 2: re-run from true init, fused ymod.
// exp path: Ad prefolded by log2(e); raw v_exp_f32 via __builtin_amdgcn_exp2f
// (NOT exp2f -- the OCML wrapper's denormal fixup cost ~18us, R1-R3 lesson).
// ---------------------------------------------------------------------------
template<bool FINAL>
__global__ __launch_bounds__(256) void scan_chunk_kernel(
    const bf16* __restrict__ delta,
    const bf16* __restrict__ xc,
    const float* __restrict__ BC,
    const float* __restrict__ A,
    float* __restrict__ Pbuf,
    float* __restrict__ Sbuf,
    const bf16* __restrict__ xz,
    const float* __restrict__ Dp,
    bf16* __restrict__ ybf)
{
    __shared__ float sBC[TCH][32];
    const int tid   = threadIdx.x;
    const int chunk = blockIdx.x;
    const int d     = blockIdx.y * 256 + tid;
    const int b     = blockIdx.z;
    const int row0  = b * LSEQ + chunk * TCH;

    {
        int t = tid >> 3, c4 = (tid & 7) * 4;
        *(float4*)&sBC[t][c4] = *(const float4*)&BC[(size_t)(row0 + t) * 32 + c4];
    }

    const float L2E = 1.4426950408889634f;
    float Ad[16];
    #pragma unroll
    for (int j = 0; j < 4; ++j) {
        float4 av = *(const float4*)&A[(size_t)d * DSTATE + j * 4];
        Ad[j*4+0] = av.x * L2E; Ad[j*4+1] = av.y * L2E;
        Ad[j*4+2] = av.z * L2E; Ad[j*4+3] = av.w * L2E;
    }

    const size_t psbase = ((size_t)(b * NC + chunk) * DSTATE) * DINNER + d;
    float S[16];
    float sumdv = 0.0f;
    if (FINAL) {
        #pragma unroll
        for (int n = 0; n < 16; ++n) S[n] = Sbuf[psbase + (size_t)n * DINNER];
    } else {
        #pragma unroll
        for (int n = 0; n < 16; ++n) S[n] = 0.0f;
    }
    float Dpd = FINAL ? Dp[d] : 0.0f;

    __syncthreads();

    #pragma unroll 2
    for (int t = 0; t < TCH; ++t) {
        const size_t row = (size_t)(row0 + t);
        float dv = (float)delta[row * DINNER + d];
        float xv = (float)xc[row * DINNER + d];
        float u  = dv * xv;
        float yp[4] = {0.f, 0.f, 0.f, 0.f};
        #pragma unroll
        for (int n = 0; n < 16; ++n) {
            float dA = __builtin_amdgcn_exp2f(dv * Ad[n]);  // bare v_exp_f32
            S[n] = dA * S[n] + u * sBC[t][n];
            if (FINAL) yp[n & 3] += S[n] * sBC[t][16 + n];
        }
        if (FINAL) {
            float y = (yp[0] + yp[1]) + (yp[2] + yp[3]);
            float res = (float)xz[row * (2 * DINNER) + DINNER + d];
            float sres = res / (1.0f + __expf(-res));
            ybf[row * DINNER + d] = (bf16)((y + xv * Dpd) * sres);
        } else {
            sumdv += dv;
        }
    }

    if (!FINAL) {
        #pragma unroll
        for (int n = 0; n < 16; ++n) {
            Pbuf[psbase + (size_t)n * DINNER] = __builtin_amdgcn_exp2f(sumdv * Ad[n]);
            Sbuf[psbase + (size_t)n * DINNER] = S[n];
        }
    }
}

// Per-(b,n,d) serial combine over chunks: Sbuf[k] <- true initial state.
__global__ __launch_bounds__(256) void scan_combine_kernel(
    const float* __restrict__ Pbuf, float* __restrict__ Sbuf)
{
    int gid = blockIdx.x * 256 + threadIdx.x;   // B * 16 * DINNER = 65536
    int b = gid >> 15;
    int nd = gid & 32767;
    float carry = 0.0f;
    for (int k = 0; k < NC; ++k) {
        size_t off = ((size_t)(b * NC + k) << 15) + nd;
        float pk = Pbuf[off];
        float sk = Sbuf[off];
        Sbuf[off] = carry;
        carry = pk * carry + sk;
    }
}

// ---------------------------------------------------------------------------
extern "C" void kernel_launch(void* const* d_in, const int* in_sizes, int n_in,
                              void* d_out, int out_size, void* d_ws, size_t ws_size,
                              hipStream_t stream)
{
    const float* x0     = (const float*)d_in[0];
    const float* norm_w = (const float*)d_in[1];
    const float* W_in   = (const float*)d_in[2];   // [1024,4096]
    const float* conv_w = (const float*)d_in[3];
    const float* conv_b = (const float*)d_in[4];
    const float* W_x    = (const float*)d_in[5];   // [2048,96]
    const float* W_dt   = (const float*)d_in[6];   // [64,2048]
    const float* b_dt   = (const float*)d_in[7];
    const float* A      = (const float*)d_in[8];
    const float* Dp     = (const float*)d_in[9];
    const float* W_out  = (const float*)d_in[10];  // [2048,1024]
    float* out = (float*)d_out;

    // Workspace layout (~84 MB)
    char* p = (char*)d_ws;
    bf16*  xz_bf = (bf16*)p;            p += (size_t)NROWS * 2 * DINNER * 2;        // 16MB
    float* Pw    = (float*)p;           p += (size_t)NSPL * NROWS * XROW * 4;       // 16MB
    float* BC    = (float*)p;           p += (size_t)NROWS * 32 * 4;                // 0.25MB
    bf16*  delta = (bf16*)p;            p += (size_t)NROWS * DINNER * 2;            // 8MB
    float* Pbuf  = (float*)p;           p += (size_t)BATCH * NC * DINNER * 16 * 4;  // 8MB
    float* Sbuf  = (float*)p;           p += (size_t)BATCH * NC * DINNER * 16 * 4;  // 8MB
    bf16*  h_bf  = (bf16*)p;            p += (size_t)NROWS * DMODEL * 2;            // 4MB
    bf16*  xc_bf = (bf16*)p;            p += (size_t)NROWS * DINNER * 2;            // 8MB
    bf16*  y_bf  = (bf16*)p;            p += (size_t)NROWS * DINNER * 2;            // 8MB
    bf16*  WinT  = (bf16*)p;            p += (size_t)(2*DINNER) * DMODEL * 2;       // 8MB
    bf16*  WxT   = (bf16*)p;            p += (size_t)XROW * DINNER * 2;             // 0.5MB
    bf16*  WdtT  = (bf16*)p;            p += (size_t)DINNER * DTRANK * 2;           // 0.25MB
    bf16*  WoutT = (bf16*)p;            p += (size_t)DMODEL * DINNER * 2;           // 4MB
    bf16*  dt_bf = (bf16*)p;            p += (size_t)NROWS * DTRANK * 2;            // 0.25MB

    // 1. Fused prep: weight transposes + RMSNorm + out<-x0 init
    prep_kernel<<<10624, 256, 0, stream>>>(W_in, WinT, W_x, WxT, W_dt, WdtT,
                                           W_out, WoutT, x0, norm_w, h_bf, out);

    // 2. xz = h @ W_in  [2048,1024]x[1024,4096] -> bf16  (TN=128, 512 blocks)
    gemm_bf16_kernel<0, true, 128, 64, false><<<dim3(32, 16, 1), 256, 0, stream>>>(
        h_bf, DMODEL, WinT, DMODEL, xz_bf, 2*DINNER, DMODEL, nullptr, nullptr, 0,
        nullptr, nullptr, nullptr, nullptr);

    // 3. x_proj split-K=16 with fused conv+silu A-staging -> Pw slices + xc
    //    grid.x==1 => disjoint A-slices per block, zero redundant conv work.
    gemm_bf16_kernel<4, false, 128, 64, true><<<dim3(1, 16, NSPL), 256, 0, stream>>>(
        nullptr, 0, WxT, DINNER, Pw, XROW, DINNER / NSPL, nullptr, nullptr, NROWS * XROW,
        xz_bf, conv_w, conv_b, xc_bf);

    // 3b. reduce partials -> dt_bf + BC
    xproj_reduce_kernel<<<(NROWS * XROW) / 256, 256, 0, stream>>>(Pw, dt_bf, BC);

    // 4. delta = softplus(dt @ W_dt + b_dt) -> bf16  (TN=128, 256 blocks)
    gemm_bf16_kernel<1, true, 128, 64, false><<<dim3(16, 16, 1), 256, 0, stream>>>(
        dt_bf, DTRANK, WdtT, DTRANK, delta, DINNER, DTRANK, b_dt, nullptr, 0,
        nullptr, nullptr, nullptr, nullptr);

    // 5. chunked selective scan (+ fused ymod) -> y_bf
    dim3 sgrid(NC, DINNER / 256, BATCH);
    scan_chunk_kernel<false><<<sgrid, 256, 0, stream>>>(
        delta, xc_bf, BC, A, Pbuf, Sbuf, nullptr, nullptr, nullptr);
    scan_combine_kernel<<<(BATCH * DINNER * DSTATE) / 256, 256, 0, stream>>>(Pbuf, Sbuf);
    scan_chunk_kernel<true><<<sgrid, 256, 0, stream>>>(
        delta, xc_bf, BC, A, Pbuf, Sbuf, xz_bf, Dp, y_bf);

    // 6. out += y @ W_out  split-K=2, atomic accumulate (out pre-init to x0)
    gemm_bf16_kernel<5, false, 64, 64, false><<<dim3(16, 16, 2), 256, 0, stream>>>(
        y_bf, DINNER, WoutT, DINNER, out, DMODEL, DINNER / 2, nullptr, nullptr, 0,
        nullptr, nullptr, nullptr, nullptr);
}